// Round 1
// baseline (275.477 us; speedup 1.0000x reference)
//
#include <hip/hip_runtime.h>
#include <math.h>

// Problem constants (reference: NUM_EXAMPLARS=200, DIM=128, F=200000 runtime)
#define N_CLS 200
#define DIM 128
#define NB1 256                         // kernel-1 grid size == number of partials
#define K1_THREADS 1024
#define PARTIAL_STRIDE (N_CLS*DIM + N_CLS)   // 25800 floats per partial block
#define INV_TEMP (1.0f/0.07f)

// ---------------------------------------------------------------------------
// Kernel 1: per-block private LDS segment histogram, flushed as fp32 partials.
// LDS column swizzle: actual column c = 4*i + j is stored at offset j*32 + i,
// so each of the 4 ds_add_f32 per float4 hits banks 0..31 (2 lanes/bank = free).
// ---------------------------------------------------------------------------
__global__ __launch_bounds__(K1_THREADS, 1)
void seg_partial_kernel(const float* __restrict__ feats,
                        const int* __restrict__ idxs,
                        float* __restrict__ partials, int F)
{
    __shared__ float hist[N_CLS * DIM];
    __shared__ int   cnt[N_CLS];
    const int t = threadIdx.x;

    for (int e = t; e < N_CLS * DIM; e += K1_THREADS) hist[e] = 0.0f;
    for (int e = t; e < N_CLS;       e += K1_THREADS) cnt[e] = 0;
    __syncthreads();

    const int lane32  = t & 31;      // column-group lane
    const int row_off = t >> 5;      // 0..31 rows per tile
    const int ntiles  = (F + 31) >> 5;
    const float4* fv  = (const float4*)feats;

    for (int tile = blockIdx.x; tile < ntiles; tile += gridDim.x) {
        int r = (tile << 5) + row_off;
        if (r < F) {
            int cls = idxs[r];
            float4 v = fv[(size_t)r * 32 + lane32];
            float* h = &hist[cls * DIM + lane32];   // swizzled storage
            atomicAdd(h + 0,  v.x);
            atomicAdd(h + 32, v.y);
            atomicAdd(h + 64, v.z);
            atomicAdd(h + 96, v.w);
            if (lane32 == 0) atomicAdd(&cnt[cls], 1);
        }
    }
    __syncthreads();

    float* out = partials + (size_t)blockIdx.x * PARTIAL_STRIDE;
    for (int e = t; e < N_CLS * DIM; e += K1_THREADS) out[e] = hist[e];
    for (int e = t; e < N_CLS;       e += K1_THREADS)
        out[N_CLS * DIM + e] = (float)cnt[e];
}

// ---------------------------------------------------------------------------
// Kernel 2: one block per class row i.
//   A: reduce partials -> row sum (swizzled order) + count -> mean_s (unswizzled)
//   B: stage examplars in LDS [200][129] (pad -> conflict-free row reads)
//   C: logits row i, log-softmax row reduction, atomicAdd scalar contribution
// ---------------------------------------------------------------------------
__device__ inline float blk_sum(float v, volatile float* wred, int t) {
    for (int o = 32; o > 0; o >>= 1) v += __shfl_down(v, o);
    __syncthreads();
    if ((t & 63) == 0) wred[t >> 6] = v;
    __syncthreads();
    return wred[0] + wred[1] + wred[2] + wred[3];
}
__device__ inline float blk_max(float v, volatile float* wred, int t) {
    for (int o = 32; o > 0; o >>= 1) v = fmaxf(v, __shfl_down(v, o));
    __syncthreads();
    if ((t & 63) == 0) wred[t >> 6] = v;
    __syncthreads();
    return fmaxf(fmaxf(wred[0], wred[1]), fmaxf(wred[2], wred[3]));
}

__global__ __launch_bounds__(256, 1)
void finish_kernel(const float* __restrict__ partials,
                   const float* __restrict__ ex,
                   float* __restrict__ out)
{
    __shared__ float ex_s[N_CLS * 129];
    __shared__ float mean_s[DIM];
    __shared__ float red[2 * DIM];
    __shared__ float wred[4];

    const int t = threadIdx.x;
    const int i = blockIdx.x;   // class / row index

    // ---- Phase A: row sums over NB1 partials (storage/swizzled order) ----
    {
        const int col_s = t & 127;
        const int half  = t >> 7;   // 0 or 1
        const float* base = partials + (size_t)i * DIM + col_s;
        float acc = 0.0f;
        #pragma unroll 8
        for (int p = half; p < NB1; p += 2)
            acc += base[(size_t)p * PARTIAL_STRIDE];
        red[half * DIM + col_s] = acc;
    }
    // counts: thread t reads partial t's count for class i (NB1 == blockDim)
    float cacc = partials[(size_t)t * PARTIAL_STRIDE + N_CLS * DIM + i];
    float count = blk_sum(cacc, wred, t);   // internal syncs also fence red[]

    if (t < DIM) {
        float m = (red[t] + red[t + DIM]) / count;
        int c = (t & 31) * 4 + (t >> 5);    // un-swizzle storage offset -> column
        mean_s[c] = m;
    }

    // ---- Phase B: stage examplars (coalesced load, padded LDS rows) ----
    for (int e = t; e < N_CLS * DIM; e += 256) {
        int r = e >> 7, c = e & 127;
        ex_s[r * 129 + c] = ex[e];
    }
    __syncthreads();

    // ---- Phase C: logits row + log-softmax reduction ----
    float logit = -INFINITY;
    if (t < N_CLS) {
        const float* er = &ex_s[t * 129];
        float dot = 0.0f, nrm = 0.0f;
        #pragma unroll 8
        for (int d = 0; d < DIM; ++d) {
            float x = er[d];
            dot += mean_s[d] * x;
            nrm += x * x;
        }
        float inv = 1.0f / fmaxf(sqrtf(nrm), 1e-12f);
        logit = dot * inv * INV_TEMP;
    }

    float mx = blk_max(logit, wred, t);
    float se = blk_sum(t < N_CLS ? expf(logit - mx) : 0.0f, wred, t);
    float sl = blk_sum(t < N_CLS ? logit : 0.0f, wred, t);

    if (t == 0) {
        float row_total = sl - (float)N_CLS * (mx + logf(se));
        atomicAdd(out, -row_total * (1.0f / ((float)N_CLS * (float)N_CLS)));
    }
}

// ---------------------------------------------------------------------------
extern "C" void kernel_launch(void* const* d_in, const int* in_sizes, int n_in,
                              void* d_out, int out_size, void* d_ws, size_t ws_size,
                              hipStream_t stream)
{
    const float* feats = (const float*)d_in[0];
    const int*   idxs  = (const int*)d_in[1];
    const float* ex    = (const float*)d_in[2];
    const int F = in_sizes[1];

    float* partials = (float*)d_ws;   // NB1 * PARTIAL_STRIDE floats = 26.4 MB

    hipMemsetAsync(d_out, 0, sizeof(float), stream);
    seg_partial_kernel<<<NB1, K1_THREADS, 0, stream>>>(feats, idxs, partials, F);
    finish_kernel<<<N_CLS, 256, 0, stream>>>(partials, ex, (float*)d_out);
}

// Round 3
// 268.549 us; speedup vs baseline: 1.0258x; 1.0258x over previous
//
#include <hip/hip_runtime.h>
#include <math.h>

// Problem constants (reference: NUM_EXAMPLARS=200, DIM=128, F=200000 runtime)
#define N_CLS 200
#define DIM 128
#define NB1 256                         // kernel-1 grid size == number of partials
#define K1_THREADS 1024
#define PARTIAL_STRIDE (N_CLS*DIM + N_CLS)   // 25800 floats per partial block
#define INV_TEMP (1.0f/0.07f)

// ---------------------------------------------------------------------------
// Kernel 1: per-block private LDS segment histogram, flushed as fp32 partials.
// LDS column swizzle: actual column c = 4*i + j is stored at offset j*32 + i,
// so each of the 4 ds_add_f32 per float4 hits banks 0..31 (2 lanes/bank = free).
// unsafeAtomicAdd emits native ds_add_f32 (fire-and-forget) instead of the
// CAS retry loop HIP otherwise generates for fp32 atomics.
// ---------------------------------------------------------------------------
__global__ __launch_bounds__(K1_THREADS, 1)
void seg_partial_kernel(const float* __restrict__ feats,
                        const int* __restrict__ idxs,
                        float* __restrict__ partials, int F)
{
    __shared__ float hist[N_CLS * DIM];
    __shared__ int   cnt[N_CLS];
    const int t = threadIdx.x;

    for (int e = t; e < N_CLS * DIM; e += K1_THREADS) hist[e] = 0.0f;
    for (int e = t; e < N_CLS;       e += K1_THREADS) cnt[e] = 0;
    __syncthreads();

    const int lane32  = t & 31;      // column-group lane
    const int row_off = t >> 5;      // 0..31 rows per tile
    const int ntiles  = (F + 31) >> 5;
    const float4* fv  = (const float4*)feats;

    for (int tile = blockIdx.x; tile < ntiles; tile += gridDim.x) {
        int r = (tile << 5) + row_off;
        if (r < F) {
            int cls = idxs[r];
            float4 v = fv[(size_t)r * 32 + lane32];
            float* h = &hist[cls * DIM + lane32];   // swizzled storage
            unsafeAtomicAdd(h + 0,  v.x);
            unsafeAtomicAdd(h + 32, v.y);
            unsafeAtomicAdd(h + 64, v.z);
            unsafeAtomicAdd(h + 96, v.w);
            if (lane32 == 0) atomicAdd(&cnt[cls], 1);   // int: native ds_add_u32
        }
    }
    __syncthreads();

    float* out = partials + (size_t)blockIdx.x * PARTIAL_STRIDE;
    for (int e = t; e < N_CLS * DIM; e += K1_THREADS) out[e] = hist[e];
    for (int e = t; e < N_CLS;       e += K1_THREADS)
        out[N_CLS * DIM + e] = (float)cnt[e];
}

// ---------------------------------------------------------------------------
// Kernel 2: one block (1024 threads) per class row i.
//   A: 32 parallel float4 streams reduce the 256 partials -> LDS tree-reduce
//   B: stage normalized-examplar rows in padded LDS
//   C: logits row i, log-softmax row reduction, atomicAdd scalar contribution
// ---------------------------------------------------------------------------
__device__ inline float blk_sum1024(float v, float* wred, int t) {
    #pragma unroll
    for (int o = 32; o > 0; o >>= 1) v += __shfl_down(v, o);
    if ((t & 63) == 0) wred[t >> 6] = v;
    __syncthreads();
    if (t < 64) {
        float x = (t < 16) ? wred[t] : 0.0f;
        #pragma unroll
        for (int o = 8; o > 0; o >>= 1) x += __shfl_down(x, o);
        if (t == 0) wred[0] = x;
    }
    __syncthreads();
    float r = wred[0];
    __syncthreads();
    return r;
}

__device__ inline float blk_max1024(float v, float* wred, int t) {
    #pragma unroll
    for (int o = 32; o > 0; o >>= 1) v = fmaxf(v, __shfl_down(v, o));
    if ((t & 63) == 0) wred[t >> 6] = v;
    __syncthreads();
    if (t < 64) {
        float x = (t < 16) ? wred[t] : -INFINITY;
        #pragma unroll
        for (int o = 8; o > 0; o >>= 1) x = fmaxf(x, __shfl_down(x, o));
        if (t == 0) wred[0] = x;
    }
    __syncthreads();
    float r = wred[0];
    __syncthreads();
    return r;
}

__global__ __launch_bounds__(1024, 1)
void finish_kernel(const float* __restrict__ partials,
                   const float* __restrict__ ex,
                   float* __restrict__ out)
{
    __shared__ float ex_s[N_CLS * 129];   // 103.2 KB
    __shared__ float redA[32 * 132];      // 16.9 KB (132 stride -> conflict-free)
    __shared__ float mean_s[DIM];
    __shared__ float wred[16];

    const int t = threadIdx.x;
    const int i = blockIdx.x;   // class / row index

    // ---- Phase A: 32 streams x float4 over the 256 partials ----
    const int q    = t >> 5;    // stream id 0..31
    const int lane = t & 31;    // float4 column 0..31
    {
        const float4* p4 = (const float4*)partials;
        // partial p, class-row i, float4 col lane: float4 index = p*(PARTIAL_STRIDE/4) + i*32 + lane
        float4 a = make_float4(0.f, 0.f, 0.f, 0.f);
        #pragma unroll
        for (int p = q; p < NB1; p += 32) {
            float4 v = p4[(size_t)p * (PARTIAL_STRIDE / 4) + (size_t)i * 32 + lane];
            a.x += v.x; a.y += v.y; a.z += v.z; a.w += v.w;
        }
        *(float4*)&redA[q * 132 + 4 * lane] = a;   // byte addr 528q+16l, 16B aligned
    }
    // counts: thread t<NB1 reads partial t's count for class i
    float cacc = (t < NB1)
        ? partials[(size_t)t * PARTIAL_STRIDE + N_CLS * DIM + i] : 0.0f;
    float count = blk_sum1024(cacc, wred, t);   // internal syncs fence redA[]

    if (t < DIM) {
        float s = 0.0f;
        #pragma unroll
        for (int q2 = 0; q2 < 32; ++q2) s += redA[q2 * 132 + t];
        // un-swizzle storage offset t -> actual column
        mean_s[4 * (t & 31) + (t >> 5)] = s / count;
    }

    // ---- Phase B: stage examplars (coalesced load, padded LDS rows) ----
    for (int e = t; e < N_CLS * DIM; e += 1024) {
        ex_s[(e >> 7) * 129 + (e & 127)] = ex[e];
    }
    __syncthreads();

    // ---- Phase C: logits row + log-softmax reduction ----
    float logit = -INFINITY;
    if (t < N_CLS) {
        const float* er = &ex_s[t * 129];
        float dot = 0.0f, nrm = 0.0f;
        #pragma unroll 8
        for (int d = 0; d < DIM; ++d) {
            float x = er[d];
            dot += mean_s[d] * x;
            nrm += x * x;
        }
        float inv = 1.0f / fmaxf(sqrtf(nrm), 1e-12f);
        logit = dot * inv * INV_TEMP;
    }

    float mx = blk_max1024(logit, wred, t);
    float se = blk_sum1024(t < N_CLS ? expf(logit - mx) : 0.0f, wred, t);
    float sl = blk_sum1024(t < N_CLS ? logit : 0.0f, wred, t);

    if (t == 0) {
        float row_total = sl - (float)N_CLS * (mx + logf(se));
        atomicAdd(out, -row_total * (1.0f / ((float)N_CLS * (float)N_CLS)));
    }
}

// ---------------------------------------------------------------------------
extern "C" void kernel_launch(void* const* d_in, const int* in_sizes, int n_in,
                              void* d_out, int out_size, void* d_ws, size_t ws_size,
                              hipStream_t stream)
{
    const float* feats = (const float*)d_in[0];
    const int*   idxs  = (const int*)d_in[1];
    const float* ex    = (const float*)d_in[2];
    const int F = in_sizes[1];

    float* partials = (float*)d_ws;   // NB1 * PARTIAL_STRIDE floats = 26.4 MB

    hipMemsetAsync(d_out, 0, sizeof(float), stream);
    seg_partial_kernel<<<NB1, K1_THREADS, 0, stream>>>(feats, idxs, partials, F);
    finish_kernel<<<N_CLS, 1024, 0, stream>>>(partials, ex, (float*)d_out);
}

// Round 9
// 225.849 us; speedup vs baseline: 1.2197x; 1.1891x over previous
//
#include <hip/hip_runtime.h>
#include <math.h>

// Problem constants (reference: NUM_EXAMPLARS=200, DIM=128, F=200000 runtime)
#define N_CLS 200
#define DIM 128
#define NB1 256                         // kernel-1 grid size == number of partials
#define K1_THREADS 1024
#define SUB 800                         // idx staging tile (>= ceil(F/NB1) = 782)
#define PARTIAL_STRIDE (N_CLS*DIM + N_CLS)   // 25800 floats per partial block
#define INV_TEMP (1.0f/0.07f)

// ---------------------------------------------------------------------------
// Kernel 1: atomic-free segment partial sums via exclusive cell ownership.
// Thread t = (m = t>>5, g = t&31) exclusively owns hist[cls][4g..4g+3] for all
// cls with (cls & 31) == m. Per row, exactly one half-wave (the 32 threads
// with matching m) takes the branch: coalesced 512B float4 load + non-atomic
// LDS read-modify-write (ds_read_b128 / ds_write_b128). No LDS atomics.
// Counts: owned by (m, g==0) threads, also non-atomic.
// ---------------------------------------------------------------------------
__global__ __launch_bounds__(K1_THREADS, 1)
void seg_partial_kernel(const float* __restrict__ feats,
                        const int* __restrict__ idxs,
                        float* __restrict__ partials,
                        float* __restrict__ out0, int F)
{
    __shared__ float hist[N_CLS * DIM];   // 102.4 KB, natural [cls][col]
    __shared__ float cntf[N_CLS];
    __shared__ int   idx_s[SUB];

    const int t = threadIdx.x;
    const int m = t >> 5;    // class-mod group 0..31
    const int g = t & 31;    // float4 column group (cols 4g..4g+3)

    if (blockIdx.x == 0 && t == 0) out0[0] = 0.0f;   // zero loss accumulator

    for (int e = t; e < N_CLS * DIM; e += K1_THREADS) hist[e] = 0.0f;
    for (int e = t; e < N_CLS;       e += K1_THREADS) cntf[e] = 0.0f;

    const float4* fv = (const float4*)feats;
    const int chunk = (F + gridDim.x - 1) / gridDim.x;
    const int r0 = blockIdx.x * chunk;
    const int r1 = min(F, r0 + chunk);

    for (int base = r0; base < r1; base += SUB) {
        const int n = min(SUB, r1 - base);
        __syncthreads();                              // idx_s reuse / hist init
        for (int e = t; e < n; e += K1_THREADS) idx_s[e] = idxs[base + e];
        __syncthreads();

        #pragma unroll 4
        for (int r = 0; r < n; ++r) {
            int cls = idx_s[r];                       // LDS broadcast read
            if ((cls & 31) == m) {                    // half-wave-uniform
                float4 v = fv[(size_t)(base + r) * 32 + g];
                float* h = &hist[cls * DIM + 4 * g];
                float4 o = *(const float4*)h;         // exclusive: no race
                o.x += v.x; o.y += v.y; o.z += v.z; o.w += v.w;
                *(float4*)h = o;
                if (g == 0) cntf[cls] += 1.0f;        // exclusive owner
            }
        }
    }
    __syncthreads();

    float* outp = partials + (size_t)blockIdx.x * PARTIAL_STRIDE;
    for (int e = t; e < N_CLS * DIM; e += K1_THREADS) outp[e] = hist[e];
    for (int e = t; e < N_CLS;       e += K1_THREADS)
        outp[N_CLS * DIM + e] = cntf[e];
}

// ---------------------------------------------------------------------------
// Kernel 2: one block (1024 threads) per class row i.
//   A: 32 parallel float4 streams reduce the 256 partials -> LDS tree-reduce
//   B: stage examplar rows in padded LDS
//   C: logits row i, log-softmax row reduction, atomicAdd scalar contribution
// ---------------------------------------------------------------------------
__device__ inline float blk_sum1024(float v, float* wred, int t) {
    #pragma unroll
    for (int o = 32; o > 0; o >>= 1) v += __shfl_down(v, o);
    if ((t & 63) == 0) wred[t >> 6] = v;
    __syncthreads();
    if (t < 64) {
        float x = (t < 16) ? wred[t] : 0.0f;
        #pragma unroll
        for (int o = 8; o > 0; o >>= 1) x += __shfl_down(x, o);
        if (t == 0) wred[0] = x;
    }
    __syncthreads();
    float r = wred[0];
    __syncthreads();
    return r;
}

__device__ inline float blk_max1024(float v, float* wred, int t) {
    #pragma unroll
    for (int o = 32; o > 0; o >>= 1) v = fmaxf(v, __shfl_down(v, o));
    if ((t & 63) == 0) wred[t >> 6] = v;
    __syncthreads();
    if (t < 64) {
        float x = (t < 16) ? wred[t] : -INFINITY;
        #pragma unroll
        for (int o = 8; o > 0; o >>= 1) x = fmaxf(x, __shfl_down(x, o));
        if (t == 0) wred[0] = x;
    }
    __syncthreads();
    float r = wred[0];
    __syncthreads();
    return r;
}

__global__ __launch_bounds__(1024, 1)
void finish_kernel(const float* __restrict__ partials,
                   const float* __restrict__ ex,
                   float* __restrict__ out)
{
    __shared__ float ex_s[N_CLS * 129];   // 103.2 KB (pad -> conflict-free rows)
    __shared__ float redA[32 * 132];      // 16.9 KB (132 stride)
    __shared__ float mean_s[DIM];
    __shared__ float wred[16];

    const int t = threadIdx.x;
    const int i = blockIdx.x;   // class / row index
    const int q    = t >> 5;    // stream id 0..31
    const int lane = t & 31;    // float4 column 0..31

    // ---- Phase A: 32 streams x float4 over the 256 partials ----
    {
        const float4* p4 = (const float4*)partials;
        float4 a = make_float4(0.f, 0.f, 0.f, 0.f);
        #pragma unroll
        for (int p = q; p < NB1; p += 32) {
            float4 v = p4[(size_t)p * (PARTIAL_STRIDE / 4) + (size_t)i * 32 + lane];
            a.x += v.x; a.y += v.y; a.z += v.z; a.w += v.w;
        }
        *(float4*)&redA[q * 132 + 4 * lane] = a;
    }
    // counts: thread t<NB1 reads partial t's count for class i
    float cacc = (t < NB1)
        ? partials[(size_t)t * PARTIAL_STRIDE + N_CLS * DIM + i] : 0.0f;
    float count = blk_sum1024(cacc, wred, t);   // internal syncs fence redA[]

    if (t < DIM) {
        float s = 0.0f;
        #pragma unroll
        for (int q2 = 0; q2 < 32; ++q2) s += redA[q2 * 132 + t];
        mean_s[t] = s / count;                  // natural column order
    }

    // ---- Phase B: stage examplars (coalesced load, padded LDS rows) ----
    for (int e = t; e < N_CLS * DIM; e += 1024) {
        ex_s[(e >> 7) * 129 + (e & 127)] = ex[e];
    }
    __syncthreads();

    // ---- Phase C: logits row + log-softmax reduction ----
    float logit = -INFINITY;
    if (t < N_CLS) {
        const float* er = &ex_s[t * 129];
        float dot = 0.0f, nrm = 0.0f;
        #pragma unroll 8
        for (int d = 0; d < DIM; ++d) {
            float x = er[d];
            dot += mean_s[d] * x;
            nrm += x * x;
        }
        float inv = 1.0f / fmaxf(sqrtf(nrm), 1e-12f);
        logit = dot * inv * INV_TEMP;
    }

    float mx = blk_max1024(logit, wred, t);
    float se = blk_sum1024(t < N_CLS ? expf(logit - mx) : 0.0f, wred, t);
    float sl = blk_sum1024(t < N_CLS ? logit : 0.0f, wred, t);

    if (t == 0) {
        float row_total = sl - (float)N_CLS * (mx + logf(se));
        atomicAdd(out, -row_total * (1.0f / ((float)N_CLS * (float)N_CLS)));
    }
}

// ---------------------------------------------------------------------------
extern "C" void kernel_launch(void* const* d_in, const int* in_sizes, int n_in,
                              void* d_out, int out_size, void* d_ws, size_t ws_size,
                              hipStream_t stream)
{
    const float* feats = (const float*)d_in[0];
    const int*   idxs  = (const int*)d_in[1];
    const float* ex    = (const float*)d_in[2];
    const int F = in_sizes[1];

    float* partials = (float*)d_ws;   // NB1 * PARTIAL_STRIDE floats = 26.4 MB

    // d_out zeroed by seg_partial_kernel (block 0) before finish_kernel runs.
    seg_partial_kernel<<<NB1, K1_THREADS, 0, stream>>>(feats, idxs, partials,
                                                       (float*)d_out, F);
    finish_kernel<<<N_CLS, K1_THREADS, 0, stream>>>(partials, ex, (float*)d_out);
}

// Round 14
// 181.347 us; speedup vs baseline: 1.5191x; 1.2454x over previous
//
#include <hip/hip_runtime.h>
#include <math.h>

// Problem constants (reference: NUM_EXAMPLARS=200, DIM=128, F=200000 runtime)
#define N_CLS 200
#define DIM 128
#define NB1 256                         // kernel-1 grid size == number of partials
#define K1_THREADS 1024
#define CHUNK_MAX 800                   // >= ceil(200000/256) = 782 rows/block
#define PARTIAL_STRIDE (N_CLS*DIM + N_CLS)   // 25800 floats per partial block
#define INV_TEMP (1.0f/0.07f)

// ---------------------------------------------------------------------------
// Kernel 1: block-local bucketing + branchless register accumulation.
// Phase 0: stage class-ids, per-class counts (int LDS atomics), 256-wide
//          prefix scan, scatter row-ids into per-class buckets.
// Phase 1: thread (m = t>>5, g = t&31) owns classes c ≡ m (mod 32), cols
//          4g..4g+3. For each owned class, iterate ONLY its rows:
//          bucket[j] is a half-wave broadcast read; the float4 load is
//          512 B coalesced across the half-wave; accumulate in REGISTERS;
//          one non-atomic float4 store per class. No fp32 LDS ops at all.
// ---------------------------------------------------------------------------
__global__ __launch_bounds__(K1_THREADS, 1)
void seg_partial_kernel(const float* __restrict__ feats,
                        const int* __restrict__ idxs,
                        float* __restrict__ partials,
                        float* __restrict__ out0, int F)
{
    __shared__ int idx_s[CHUNK_MAX];
    __shared__ int bucket[CHUNK_MAX];
    __shared__ int cnt[N_CLS];
    __shared__ int start_s[N_CLS];
    __shared__ int cursor[N_CLS];
    __shared__ int scan_s[256];

    const int t = threadIdx.x;
    const int b = blockIdx.x;
    if (b == 0 && t == 0) out0[0] = 0.0f;   // zero loss accumulator

    const int chunk = (F + NB1 - 1) / NB1;
    const int r0 = b * chunk;
    const int n  = min(F, r0 + chunk) - r0;     // 782 (590 for last block)

    for (int e = t; e < N_CLS; e += K1_THREADS) { cnt[e] = 0; cursor[e] = 0; }
    for (int e = t; e < n; e += K1_THREADS) idx_s[e] = idxs[r0 + e];
    __syncthreads();

    // ---- per-class counts (native int LDS atomics) ----
    for (int e = t; e < n; e += K1_THREADS) atomicAdd(&cnt[idx_s[e]], 1);
    __syncthreads();

    // ---- Hillis-Steele inclusive scan over 256 (cnt zero-padded) ----
    if (t < 256) scan_s[t] = (t < N_CLS) ? cnt[t] : 0;
    __syncthreads();
    for (int d = 1; d < 256; d <<= 1) {
        int x = 0;
        if (t < 256) { x = scan_s[t]; if (t >= d) x += scan_s[t - d]; }
        __syncthreads();
        if (t < 256) scan_s[t] = x;
        __syncthreads();
    }
    if (t < N_CLS) start_s[t] = scan_s[t] - cnt[t];   // exclusive start
    __syncthreads();

    // ---- scatter row-ids into class buckets ----
    for (int e = t; e < n; e += K1_THREADS) {
        int c = idx_s[e];
        int pos = atomicAdd(&cursor[c], 1);
        bucket[start_s[c] + pos] = e;
    }
    __syncthreads();

    // ---- Phase 1: branchless register accumulation ----
    const int m = t >> 5;    // class-mod group 0..31 (half-wave)
    const int g = t & 31;    // float4 column group (cols 4g..4g+3)
    const float4* fv = (const float4*)feats;
    float* outp = partials + (size_t)b * PARTIAL_STRIDE;

    for (int c = m; c < N_CLS; c += 32) {
        const int s  = start_s[c];
        const int e  = s + cnt[c];
        float4 acc = make_float4(0.f, 0.f, 0.f, 0.f);
        for (int j = s; j < e; ++j) {
            int r = bucket[j];                         // half-wave broadcast
            float4 v = fv[(size_t)(r0 + r) * 32 + g];  // 512B coalesced
            acc.x += v.x; acc.y += v.y; acc.z += v.z; acc.w += v.w;
        }
        *(float4*)&outp[c * DIM + 4 * g] = acc;        // plain store
    }
    // counts final since the post-count barrier; no extra sync needed
    for (int e2 = t; e2 < N_CLS; e2 += K1_THREADS)
        outp[N_CLS * DIM + e2] = (float)cnt[e2];
}

// ---------------------------------------------------------------------------
// Kernel 2: one block (1024 threads) per class row i.  (unchanged from R9)
//   A: 32 parallel float4 streams reduce the 256 partials -> LDS tree-reduce
//   B: stage examplar rows in padded LDS
//   C: logits row i, log-softmax row reduction, atomicAdd scalar contribution
// ---------------------------------------------------------------------------
__device__ inline float blk_sum1024(float v, float* wred, int t) {
    #pragma unroll
    for (int o = 32; o > 0; o >>= 1) v += __shfl_down(v, o);
    if ((t & 63) == 0) wred[t >> 6] = v;
    __syncthreads();
    if (t < 64) {
        float x = (t < 16) ? wred[t] : 0.0f;
        #pragma unroll
        for (int o = 8; o > 0; o >>= 1) x += __shfl_down(x, o);
        if (t == 0) wred[0] = x;
    }
    __syncthreads();
    float r = wred[0];
    __syncthreads();
    return r;
}

__device__ inline float blk_max1024(float v, float* wred, int t) {
    #pragma unroll
    for (int o = 32; o > 0; o >>= 1) v = fmaxf(v, __shfl_down(v, o));
    if ((t & 63) == 0) wred[t >> 6] = v;
    __syncthreads();
    if (t < 64) {
        float x = (t < 16) ? wred[t] : -INFINITY;
        #pragma unroll
        for (int o = 8; o > 0; o >>= 1) x = fmaxf(x, __shfl_down(x, o));
        if (t == 0) wred[0] = x;
    }
    __syncthreads();
    float r = wred[0];
    __syncthreads();
    return r;
}

__global__ __launch_bounds__(1024, 1)
void finish_kernel(const float* __restrict__ partials,
                   const float* __restrict__ ex,
                   float* __restrict__ out)
{
    __shared__ float ex_s[N_CLS * 129];   // 103.2 KB (pad -> conflict-free rows)
    __shared__ float redA[32 * 132];      // 16.9 KB (132 stride)
    __shared__ float mean_s[DIM];
    __shared__ float wred[16];

    const int t = threadIdx.x;
    const int i = blockIdx.x;   // class / row index
    const int q    = t >> 5;    // stream id 0..31
    const int lane = t & 31;    // float4 column 0..31

    // ---- Phase A: 32 streams x float4 over the 256 partials ----
    {
        const float4* p4 = (const float4*)partials;
        float4 a = make_float4(0.f, 0.f, 0.f, 0.f);
        #pragma unroll
        for (int p = q; p < NB1; p += 32) {
            float4 v = p4[(size_t)p * (PARTIAL_STRIDE / 4) + (size_t)i * 32 + lane];
            a.x += v.x; a.y += v.y; a.z += v.z; a.w += v.w;
        }
        *(float4*)&redA[q * 132 + 4 * lane] = a;
    }
    // counts: thread t<NB1 reads partial t's count for class i
    float cacc = (t < NB1)
        ? partials[(size_t)t * PARTIAL_STRIDE + N_CLS * DIM + i] : 0.0f;
    float count = blk_sum1024(cacc, wred, t);   // internal syncs fence redA[]

    if (t < DIM) {
        float s = 0.0f;
        #pragma unroll
        for (int q2 = 0; q2 < 32; ++q2) s += redA[q2 * 132 + t];
        mean_s[t] = s / count;                  // natural column order
    }

    // ---- Phase B: stage examplars (coalesced load, padded LDS rows) ----
    for (int e = t; e < N_CLS * DIM; e += 1024) {
        ex_s[(e >> 7) * 129 + (e & 127)] = ex[e];
    }
    __syncthreads();

    // ---- Phase C: logits row + log-softmax reduction ----
    float logit = -INFINITY;
    if (t < N_CLS) {
        const float* er = &ex_s[t * 129];
        float dot = 0.0f, nrm = 0.0f;
        #pragma unroll 8
        for (int d = 0; d < DIM; ++d) {
            float x = er[d];
            dot += mean_s[d] * x;
            nrm += x * x;
        }
        float inv = 1.0f / fmaxf(sqrtf(nrm), 1e-12f);
        logit = dot * inv * INV_TEMP;
    }

    float mx = blk_max1024(logit, wred, t);
    float se = blk_sum1024(t < N_CLS ? expf(logit - mx) : 0.0f, wred, t);
    float sl = blk_sum1024(t < N_CLS ? logit : 0.0f, wred, t);

    if (t == 0) {
        float row_total = sl - (float)N_CLS * (mx + logf(se));
        atomicAdd(out, -row_total * (1.0f / ((float)N_CLS * (float)N_CLS)));
    }
}

// ---------------------------------------------------------------------------
extern "C" void kernel_launch(void* const* d_in, const int* in_sizes, int n_in,
                              void* d_out, int out_size, void* d_ws, size_t ws_size,
                              hipStream_t stream)
{
    const float* feats = (const float*)d_in[0];
    const int*   idxs  = (const int*)d_in[1];
    const float* ex    = (const float*)d_in[2];
    const int F = in_sizes[1];

    float* partials = (float*)d_ws;   // NB1 * PARTIAL_STRIDE floats = 26.4 MB

    // d_out zeroed by seg_partial_kernel (block 0) before finish_kernel runs.
    seg_partial_kernel<<<NB1, K1_THREADS, 0, stream>>>(feats, idxs, partials,
                                                       (float*)d_out, F);
    finish_kernel<<<N_CLS, K1_THREADS, 0, stream>>>(partials, ex, (float*)d_out);
}